// Round 7
// baseline (88.121 us; speedup 1.0000x reference)
//
#include <hip/hip_runtime.h>

#define W 512
#define H 512
#define OWID 506
#define OHT 506
#define BC 48              // 16 images * 3 channels
#define KC 2               // output cols per lane
#define STRIPW 128         // 64 lanes * KC
#define NSTRIP 4           // 4*128 = 512 >= 506
#define CH 21              // output rows per chunk (3 groups of 7)
#define NCHUNK 25          // 25*21 = 525 >= 506
#define NWAVE (BC*NSTRIP*NCHUNK)   // 4800, divisible by 4
#define NPIX 12289728.0f           // 16*3*506*506

__device__ __forceinline__ float clip01(float v) { return fminf(fmaxf(v, 0.f), 1.f); }

struct R5 { float2 h0, h1, h2, h3, h4; };   // hsum pairs (colA,colB) x 5 quantities

// hA = p0+..+p6, hB = p1+..+p7 via shared middle (7 adds)
__device__ __forceinline__ float2 hsum2(const float p[8]) {
    float m = p[1] + p[2] + p[3] + p[4] + p[5] + p[6];
    float2 r; r.x = m + p[0]; r.y = m + p[7]; return r;
}

__device__ __forceinline__ R5 hrow(const float2 rx[4], const float2 ry[4]) {
    float x[8], y[8], p[8];
    #pragma unroll
    for (int j = 0; j < 4; ++j) {
        x[2*j] = clip01(rx[j].x); x[2*j+1] = clip01(rx[j].y);
        y[2*j] = clip01(ry[j].x); y[2*j+1] = clip01(ry[j].y);
    }
    R5 o;
    o.h0 = hsum2(x);
    o.h1 = hsum2(y);
    #pragma unroll
    for (int j = 0; j < 8; ++j) p[j] = x[j] * x[j];
    o.h2 = hsum2(p);
    #pragma unroll
    for (int j = 0; j < 8; ++j) p[j] = y[j] * y[j];
    o.h3 = hsum2(p);
    #pragma unroll
    for (int j = 0; j < 8; ++j) p[j] = x[j] * y[j];
    o.h4 = hsum2(p);
    return o;
}

__device__ __forceinline__ void ldrow(const float* __restrict__ pr,
                                      const float* __restrict__ tr,
                                      const int co[4], float2 rx[4], float2 ry[4]) {
    #pragma unroll
    for (int j = 0; j < 4; ++j) {
        rx[j] = *(const float2*)(pr + co[j]);
        ry[j] = *(const float2*)(tr + co[j]);
    }
}

__device__ __forceinline__ void upd(float2& s, const float2 a, const float2 b) {
    s.x += a.x - b.x;
    s.y += a.y - b.y;
}

// sum-domain SSIM (scaled by 49^4): a0..a4 = window sums of x,y,xx,yy,xy
__device__ __forceinline__ float ssim_v(float a0, float a1, float a2, float a3, float a4) {
    const float c1p   = 0.2401f;        // C1 * 49^2
    const float c2p   = 2.1609f;        // C2 * 49^2
    const float covn  = 49.0f / 48.0f;
    const float covn2 = 49.0f / 24.0f;
    float t01  = a0 * a1;
    float qs   = fmaf(a0, a0, a1 * a1);
    float w4   = fmaf(49.f, a4, -t01);
    float num1 = fmaf(2.f, t01, c1p);
    float num2 = fmaf(covn2, w4, c2p);
    float s23  = a2 + a3;
    float w23  = fmaf(49.f, s23, -qs);
    float den1 = qs + c1p;
    float den2 = fmaf(covn, w23, c2p);
    return (num1 * num2) * __builtin_amdgcn_rcpf(den1 * den2);
}

__global__ __launch_bounds__(256, 3)
void ssim_stream(const float* __restrict__ pred, const float* __restrict__ targ,
                 float* __restrict__ partial, float* __restrict__ out_atomic)
{
    const int wid  = __builtin_amdgcn_readfirstlane(blockIdx.x * 4 + (threadIdx.x >> 6));
    const int lane = threadIdx.x & 63;

    const int bc    = wid / (NSTRIP * NCHUNK);
    const int rem   = wid - bc * (NSTRIP * NCHUNK);
    const int strip = rem / NCHUNK;
    const int chunk = rem - strip * NCHUNK;

    const int b = strip * STRIPW + 2 * lane;     // first owned output col
    int co[4];
    #pragma unroll
    for (int j = 0; j < 4; ++j) co[j] = min(b + 2 * j, W - 2);  // clamped float2 col
    const bool ok0 = (b     < OWID);
    const bool ok1 = (b + 1 < OWID);

    const int oy0 = chunk * CH;
    const size_t base = (size_t)bc * (H * W) + (size_t)oy0 * W;
    const float* __restrict__ px = pred + base;
    const float* __restrict__ py = targ + base;

    // ---- init: rows 0..6 with one-row-ahead prefetch ----
    float2 nx[4], ny[4], cx[4], cy[4];
    ldrow(px, py, co, nx, ny);                   // row 0
    R5 ring[7];
    float2 s0 = {0,0}, s1 = {0,0}, s2 = {0,0}, s3 = {0,0}, s4 = {0,0};
    #pragma unroll
    for (int i = 0; i < 7; ++i) {
        #pragma unroll
        for (int j = 0; j < 4; ++j) { cx[j] = nx[j]; cy[j] = ny[j]; }
        ldrow(px + (i + 1) * W, py + (i + 1) * W, co, nx, ny);   // rows 1..7 (<=511)
        ring[i] = hrow(cx, cy);
        upd(s0, ring[i].h0, make_float2(0,0));
        upd(s1, ring[i].h1, make_float2(0,0));
        upd(s2, ring[i].h2, make_float2(0,0));
        upd(s3, ring[i].h3, make_float2(0,0));
        upd(s4, ring[i].h4, make_float2(0,0));
    }
    // nx/ny now hold row 7. Scalar prefetch pointers for row 8+, clamped.
    const int r8 = min(oy0 + 8, H - 1) - oy0;
    const float* fx = px + r8 * W;
    const float* fy = py + r8 * W;
    int rabs = oy0 + 8;

    float acc = 0.f;

    #pragma unroll 1
    for (int g = 0; g < 3; ++g) {
        if (oy0 + 7 * g >= OHT) break;           // scalar early-exit (last chunk)
        #pragma unroll
        for (int i = 0; i < 7; ++i) {            // t = 7g+i, ring slot i (static)
            const int t = g * 7 + i;
            // ---- emit output row oy0+t ----
            {
                float v0 = ssim_v(s0.x, s1.x, s2.x, s3.x, s4.x);
                float v1 = ssim_v(s0.y, s1.y, s2.y, s3.y, s4.y);
                bool rok = (oy0 + t) < OHT;      // scalar
                acc += (ok0 && rok) ? v0 : 0.f;
                acc += (ok1 && rok) ? v1 : 0.f;
            }
            // ---- advance: consume prefetched row t+7, prefetch row t+8 ----
            {
                #pragma unroll
                for (int j = 0; j < 4; ++j) { cx[j] = nx[j]; cy[j] = ny[j]; }
                ldrow(fx, fy, co, nx, ny);
                if (rabs < H - 1) { fx += W; fy += W; }  // scalar guard
                ++rabs;
                R5 nr = hrow(cx, cy);
                upd(s0, nr.h0, ring[i].h0);
                upd(s1, nr.h1, ring[i].h1);
                upd(s2, nr.h2, ring[i].h2);
                upd(s3, nr.h3, ring[i].h3);
                upd(s4, nr.h4, ring[i].h4);
                ring[i] = nr;
            }
        }
    }

    // ---- wave reduction, one partial per wave ----
    #pragma unroll
    for (int off = 32; off >= 1; off >>= 1)
        acc += __shfl_down(acc, off, 64);
    if (lane == 0) {
        if (partial) partial[wid] = acc;
        else atomicAdd(out_atomic, acc);
    }
}

__global__ __launch_bounds__(256)
void ssim_finish(const float* __restrict__ partial, float* __restrict__ out)
{
    __shared__ float red[4];
    float s = 0.f;
    for (int i = threadIdx.x; i < NWAVE; i += 256) s += partial[i];
    #pragma unroll
    for (int off = 32; off >= 1; off >>= 1)
        s += __shfl_down(s, off, 64);
    if ((threadIdx.x & 63) == 0) red[threadIdx.x >> 6] = s;
    __syncthreads();
    if (threadIdx.x == 0) {
        float t = red[0] + red[1] + red[2] + red[3];
        out[0] = 1.0f - t / NPIX;
    }
}

__global__ void ssim_zero(float* out) { out[0] = 0.0f; }
__global__ void ssim_finish_atomic(float* out) { out[0] = 1.0f - out[0] / NPIX; }

extern "C" void kernel_launch(void* const* d_in, const int* in_sizes, int n_in,
                              void* d_out, int out_size, void* d_ws, size_t ws_size,
                              hipStream_t stream) {
    const float* pred = (const float*)d_in[0];
    const float* targ = (const float*)d_in[1];
    float* out = (float*)d_out;

    dim3 block(256);
    dim3 grid(NWAVE / 4);   // 1200 blocks, 4 waves each

    if (ws_size >= (size_t)NWAVE * sizeof(float)) {
        float* part = (float*)d_ws;
        ssim_stream<<<grid, block, 0, stream>>>(pred, targ, part, nullptr);
        ssim_finish<<<1, 256, 0, stream>>>(part, out);
    } else {
        ssim_zero<<<1, 1, 0, stream>>>(out);
        ssim_stream<<<grid, block, 0, stream>>>(pred, targ, nullptr, out);
        ssim_finish_atomic<<<1, 1, 0, stream>>>(out);
    }
}

// Round 8
// 49.254 us; speedup vs baseline: 1.7891x; 1.7891x over previous
//
#include <hip/hip_runtime.h>

#define W 512
#define H 512
#define OWID 506
#define OHT 506
#define BC 48              // 16 images * 3 channels
#define SEGW 10            // valid outputs per 16-lane segment
#define SWOUT 40           // outputs per wave (4 segments)
#define NSTRIP 13          // ceil(506/40)
#define CH 42              // output rows per chunk (6 groups of 7)
#define NCHUNK 13          // 13*42 = 546 >= 506
#define NWAVE (BC*NSTRIP*NCHUNK)   // 8112, divisible by 4
#define NPIX 12289728.0f           // 16*3*506*506

__device__ __forceinline__ float clip01(float v) { return fminf(fmaxf(v, 0.f), 1.f); }

// DPP row_shl:N — lane p receives lane p+N within its 16-lane row; 0 if OOB.
template <int N>
__device__ __forceinline__ float dpp_shl(float v) {
    int r = __builtin_amdgcn_update_dpp(0, __float_as_int(v),
                                        0x100 + N, 0xF, 0xF, true);
    return __int_as_float(r);
}

// sum of v over lane positions p..p+6 (valid for p<=9 within each 16-lane row)
__device__ __forceinline__ float hsum7(float v) {
    float a1 = v + dpp_shl<1>(v);        // v[p]+v[p+1]
    float a2 = a1 + dpp_shl<2>(a1);      // v[p..p+3]
    return a2 + dpp_shl<4>(a1)           // + v[p+4]+v[p+5]
              + dpp_shl<6>(v);           // + v[p+6]
}

__global__ __launch_bounds__(256)
void ssim_stream(const float* __restrict__ pred, const float* __restrict__ targ,
                 float* __restrict__ partial, float* __restrict__ out_atomic)
{
    // wave-uniform id -> SGPR addressing, scalar row pointers
    const int wid  = __builtin_amdgcn_readfirstlane(blockIdx.x * 4 + (threadIdx.x >> 6));
    const int lane = threadIdx.x & 63;
    const int seg  = lane >> 4;
    const int pos  = lane & 15;

    const int bc    = wid / (NSTRIP * NCHUNK);
    const int rem   = wid - bc * (NSTRIP * NCHUNK);
    const int strip = rem / NCHUNK;
    const int chunk = rem - strip * NCHUNK;

    const int gx  = strip * SWOUT + seg * SEGW + pos;  // pixel col / output col
    const int gxc = min(gx, W - 1);
    const int oy0 = chunk * CH;
    const bool colok = (pos <= 9) && (gx < OWID);

    const size_t base = (size_t)bc * (H * W) + (size_t)oy0 * W;
    const float* __restrict__ px = pred + base;   // scalar base, row oy0
    const float* __restrict__ py = targ + base;

    // ---- vertical-first state: ring of clipped raw values, running col sums ----
    float ringx[7], ringy[7];
    float Vx = 0.f, Vy = 0.f, Vz = 0.f, Vxy = 0.f;   // per-col sums of x,y,x^2+y^2,xy

    // init rows 0..6 with one-row-ahead prefetch (rows <= 511, in-bounds)
    float nx = px[gxc];
    float ny = py[gxc];
    #pragma unroll
    for (int i = 0; i < 7; ++i) {
        float xr = nx, yr = ny;
        nx = px[(i + 1) * W + gxc];
        ny = py[(i + 1) * W + gxc];
        float x = clip01(xr), y = clip01(yr);
        ringx[i] = x; ringy[i] = y;
        Vx += x; Vy += y;
        Vz  = fmaf(x, x, Vz);  Vz = fmaf(y, y, Vz);
        Vxy = fmaf(x, y, Vxy);
    }
    // nx/ny hold row 7. Scalar prefetch pointers for row 8+, clamped (R5 fix).
    const int r8 = min(oy0 + 8, H - 1) - oy0;
    const float* fx = px + r8 * W;
    const float* fy = py + r8 * W;
    int rabs = oy0 + 8;

    // sum-domain SSIM constants (num/den scaled by 49^4)
    const float c1p   = 0.2401f;        // C1 * 49^2
    const float c2p   = 2.1609f;        // C2 * 49^2
    const float covn  = 49.0f / 48.0f;
    const float covn2 = 49.0f / 24.0f;  // 2*covn
    float acc = 0.f;

    #pragma unroll 1
    for (int g = 0; g < 6; ++g) {
        if (oy0 + 7 * g >= OHT) break;     // scalar early-exit (last chunk)
        #pragma unroll
        for (int i = 0; i < 7; ++i) {      // t = 7g+i, ring slot i (static)
            const int t = g * 7 + i;
            // ---- emit output row oy0+t: horizontal 7-sums of vertical sums ----
            {
                float a0 = hsum7(Vx);
                float a1 = hsum7(Vy);
                float az = hsum7(Vz);
                float a4 = hsum7(Vxy);
                float t01  = a0 * a1;
                float qs   = fmaf(a0, a0, a1 * a1);
                float w4   = fmaf(49.f, a4, -t01);
                float num1 = fmaf(2.f, t01, c1p);
                float num2 = fmaf(covn2, w4, c2p);
                float w23  = fmaf(49.f, az, -qs);
                float den1 = qs + c1p;
                float den2 = fmaf(covn, w23, c2p);
                float v = (num1 * num2) * __builtin_amdgcn_rcpf(den1 * den2);
                bool ok = colok && (oy0 + t < OHT);   // row check is scalar
                acc += ok ? v : 0.f;
            }
            // ---- advance: consume prefetched row t+7, prefetch row t+8 ----
            {
                float xo = ringx[i], yo = ringy[i];
                float xn = clip01(nx), yn = clip01(ny);
                nx = fx[gxc];
                ny = fy[gxc];
                if (rabs < H - 1) { fx += W; fy += W; }  // scalar guard
                ++rabs;
                Vx += xn - xo;
                Vy += yn - yo;
                float zn = fmaf(xn, xn, yn * yn);
                float zo = fmaf(xo, xo, yo * yo);
                Vz += zn - zo;
                Vxy += fmaf(xn, yn, -(xo * yo));
                ringx[i] = xn; ringy[i] = yn;
            }
        }
    }

    // ---- wave reduction, one partial per wave ----
    #pragma unroll
    for (int off = 32; off >= 1; off >>= 1)
        acc += __shfl_down(acc, off, 64);
    if (lane == 0) {
        if (partial) partial[wid] = acc;
        else atomicAdd(out_atomic, acc);
    }
}

__global__ __launch_bounds__(256)
void ssim_finish(const float* __restrict__ partial, float* __restrict__ out)
{
    __shared__ float red[4];
    float s = 0.f;
    for (int i = threadIdx.x; i < NWAVE; i += 256) s += partial[i];
    #pragma unroll
    for (int off = 32; off >= 1; off >>= 1)
        s += __shfl_down(s, off, 64);
    if ((threadIdx.x & 63) == 0) red[threadIdx.x >> 6] = s;
    __syncthreads();
    if (threadIdx.x == 0) {
        float t = red[0] + red[1] + red[2] + red[3];
        out[0] = 1.0f - t / NPIX;
    }
}

__global__ void ssim_zero(float* out) { out[0] = 0.0f; }
__global__ void ssim_finish_atomic(float* out) { out[0] = 1.0f - out[0] / NPIX; }

extern "C" void kernel_launch(void* const* d_in, const int* in_sizes, int n_in,
                              void* d_out, int out_size, void* d_ws, size_t ws_size,
                              hipStream_t stream) {
    const float* pred = (const float*)d_in[0];
    const float* targ = (const float*)d_in[1];
    float* out = (float*)d_out;

    dim3 block(256);
    dim3 grid(NWAVE / 4);   // 2028 blocks, 4 waves each

    if (ws_size >= (size_t)NWAVE * sizeof(float)) {
        float* part = (float*)d_ws;
        ssim_stream<<<grid, block, 0, stream>>>(pred, targ, part, nullptr);
        ssim_finish<<<1, 256, 0, stream>>>(part, out);
    } else {
        ssim_zero<<<1, 1, 0, stream>>>(out);
        ssim_stream<<<grid, block, 0, stream>>>(pred, targ, nullptr, out);
        ssim_finish_atomic<<<1, 1, 0, stream>>>(out);
    }
}

// Round 9
// 40.460 us; speedup vs baseline: 2.1780x; 1.2174x over previous
//
#include <hip/hip_runtime.h>

#define W 512
#define H 512
#define OWID 506
#define OHT 506
#define BC 48              // 16 images * 3 channels
#define SEGOUT 26          // valid output cols per 16-lane segment (2/lane, q<=12)
#define WAVEOUT 104        // 4 segments
#define NSTRIP 5           // 5*104 = 520 >= 506
#define CH 21              // output rows per chunk (3 groups of 7)
#define NCHUNK 25          // 25*21 = 525 >= 506
#define NWAVE (BC*NSTRIP*NCHUNK)   // 6000, divisible by 4
#define NPIX 12289728.0f           // 16*3*506*506

__device__ __forceinline__ float clip01(float v) { return fminf(fmaxf(v, 0.f), 1.f); }

// DPP row_shl:N — lane p receives lane p+N within its 16-lane row; 0 if OOB.
template <int N>
__device__ __forceinline__ float dpp_shl(float v) {
    int r = __builtin_amdgcn_update_dpp(0, __float_as_int(v),
                                        0x100 + N, 0xF, 0xF, true);
    return __int_as_float(r);
}

// V = (even-col sum, odd-col sum). Returns (h for col 2q, h for col 2q+1).
// P=Ve+Vo; S4 = 8-col sum (lanes q..q+3); h_e = S4 - col(2q+7); h_o = S4 - col(2q).
__device__ __forceinline__ float2 hpair(float2 V) {
    float P  = V.x + V.y;
    float S2 = P + dpp_shl<1>(P);
    float S4 = S2 + dpp_shl<2>(S2);
    float2 h;
    h.x = S4 - dpp_shl<3>(V.y);
    h.y = S4 - V.x;
    return h;
}

// sum-domain SSIM (scaled by 49^4)
__device__ __forceinline__ float ssim_v(float a0, float a1, float az, float a4) {
    const float c1p   = 0.2401f;        // C1 * 49^2
    const float c2p   = 2.1609f;        // C2 * 49^2
    const float covn  = 49.0f / 48.0f;
    const float covn2 = 49.0f / 24.0f;
    float t01  = a0 * a1;
    float qs   = fmaf(a0, a0, a1 * a1);
    float w4   = fmaf(49.f, a4, -t01);
    float num1 = fmaf(2.f, t01, c1p);
    float num2 = fmaf(covn2, w4, c2p);
    float w23  = fmaf(49.f, az, -qs);
    float den1 = qs + c1p;
    float den2 = fmaf(covn, w23, c2p);
    return (num1 * num2) * __builtin_amdgcn_rcpf(den1 * den2);
}

__global__ __launch_bounds__(256)
void ssim_stream(const float* __restrict__ pred, const float* __restrict__ targ,
                 float* __restrict__ partial, float* __restrict__ out_atomic)
{
    // wave-uniform id -> SGPR addressing, scalar row pointers
    const int wid  = __builtin_amdgcn_readfirstlane(blockIdx.x * 4 + (threadIdx.x >> 6));
    const int lane = threadIdx.x & 63;
    const int seg  = lane >> 4;
    const int q    = lane & 15;

    const int bc    = wid / (NSTRIP * NCHUNK);
    const int rem   = wid - bc * (NSTRIP * NCHUNK);
    const int strip = rem / NCHUNK;
    const int chunk = rem - strip * NCHUNK;

    const int ce = strip * WAVEOUT + seg * SEGOUT + 2 * q;  // even col this lane owns
    const int co = min(ce, W - 2);                          // clamped float2 col
    const bool oke = (q <= 12) && (ce     < OWID);
    const bool oko = (q <= 12) && (ce + 1 < OWID);

    const int oy0 = chunk * CH;
    const size_t base = (size_t)bc * (H * W) + (size_t)oy0 * W;
    const float* __restrict__ px = pred + base;   // scalar base, row oy0
    const float* __restrict__ py = targ + base;

    // ---- vertical-first state: ring of clipped pairs, running pair sums ----
    float2 ringx[7], ringy[7];
    float2 Vx = {0,0}, Vy = {0,0}, Vz = {0,0}, Vxy = {0,0};

    float2 nx = *(const float2*)(px + co);
    float2 ny = *(const float2*)(py + co);
    #pragma unroll
    for (int i = 0; i < 7; ++i) {
        float2 xr = nx, yr = ny;
        nx = *(const float2*)(px + (i + 1) * W + co);   // rows 1..7 (<=511)
        ny = *(const float2*)(py + (i + 1) * W + co);
        float2 x, y;
        x.x = clip01(xr.x); x.y = clip01(xr.y);
        y.x = clip01(yr.x); y.y = clip01(yr.y);
        ringx[i] = x; ringy[i] = y;
        Vx.x += x.x; Vx.y += x.y;
        Vy.x += y.x; Vy.y += y.y;
        Vz.x  = fmaf(x.x, x.x, Vz.x);  Vz.x  = fmaf(y.x, y.x, Vz.x);
        Vz.y  = fmaf(x.y, x.y, Vz.y);  Vz.y  = fmaf(y.y, y.y, Vz.y);
        Vxy.x = fmaf(x.x, y.x, Vxy.x);
        Vxy.y = fmaf(x.y, y.y, Vxy.y);
    }
    // nx/ny hold row 7. Scalar prefetch pointers for row 8+, clamped.
    const int r8 = min(oy0 + 8, H - 1) - oy0;
    const float* fx = px + r8 * W;
    const float* fy = py + r8 * W;
    int rabs = oy0 + 8;

    float acc = 0.f;

    #pragma unroll 1
    for (int g = 0; g < 3; ++g) {
        if (oy0 + 7 * g >= OHT) break;     // scalar early-exit (last chunk)
        #pragma unroll
        for (int i = 0; i < 7; ++i) {      // t = 7g+i, ring slot i (static)
            const int t = g * 7 + i;
            // ---- emit output row oy0+t: shared-ladder h-pairs, 2 cols/lane ----
            {
                float2 hx = hpair(Vx);
                float2 hy = hpair(Vy);
                float2 hz = hpair(Vz);
                float2 hw = hpair(Vxy);
                float ve = ssim_v(hx.x, hy.x, hz.x, hw.x);
                float vo = ssim_v(hx.y, hy.y, hz.y, hw.y);
                bool rok = (oy0 + t) < OHT;          // scalar
                acc += (oke && rok) ? ve : 0.f;
                acc += (oko && rok) ? vo : 0.f;
            }
            // ---- advance: consume prefetched row t+7, prefetch row t+8 ----
            {
                float2 xo = ringx[i], yo = ringy[i];
                float2 xn, yn;
                xn.x = clip01(nx.x); xn.y = clip01(nx.y);
                yn.x = clip01(ny.x); yn.y = clip01(ny.y);
                nx = *(const float2*)(fx + co);
                ny = *(const float2*)(fy + co);
                if (rabs < H - 1) { fx += W; fy += W; }  // scalar guard
                ++rabs;
                Vx.x += xn.x - xo.x;  Vx.y += xn.y - xo.y;
                Vy.x += yn.x - yo.x;  Vy.y += yn.y - yo.y;
                float zne = fmaf(xn.x, xn.x, yn.x * yn.x);
                float zoe = fmaf(xo.x, xo.x, yo.x * yo.x);
                float zno = fmaf(xn.y, xn.y, yn.y * yn.y);
                float zoo = fmaf(xo.y, xo.y, yo.y * yo.y);
                Vz.x += zne - zoe;    Vz.y += zno - zoo;
                Vxy.x += fmaf(xn.x, yn.x, -(xo.x * yo.x));
                Vxy.y += fmaf(xn.y, yn.y, -(xo.y * yo.y));
                ringx[i] = xn; ringy[i] = yn;
            }
        }
    }

    // ---- wave reduction, one partial per wave ----
    #pragma unroll
    for (int off = 32; off >= 1; off >>= 1)
        acc += __shfl_down(acc, off, 64);
    if (lane == 0) {
        if (partial) partial[wid] = acc;
        else atomicAdd(out_atomic, acc);
    }
}

__global__ __launch_bounds__(256)
void ssim_finish(const float* __restrict__ partial, float* __restrict__ out)
{
    __shared__ float red[4];
    float s = 0.f;
    for (int i = threadIdx.x; i < NWAVE; i += 256) s += partial[i];
    #pragma unroll
    for (int off = 32; off >= 1; off >>= 1)
        s += __shfl_down(s, off, 64);
    if ((threadIdx.x & 63) == 0) red[threadIdx.x >> 6] = s;
    __syncthreads();
    if (threadIdx.x == 0) {
        float t = red[0] + red[1] + red[2] + red[3];
        out[0] = 1.0f - t / NPIX;
    }
}

__global__ void ssim_zero(float* out) { out[0] = 0.0f; }
__global__ void ssim_finish_atomic(float* out) { out[0] = 1.0f - out[0] / NPIX; }

extern "C" void kernel_launch(void* const* d_in, const int* in_sizes, int n_in,
                              void* d_out, int out_size, void* d_ws, size_t ws_size,
                              hipStream_t stream) {
    const float* pred = (const float*)d_in[0];
    const float* targ = (const float*)d_in[1];
    float* out = (float*)d_out;

    dim3 block(256);
    dim3 grid(NWAVE / 4);   // 1500 blocks, 4 waves each

    if (ws_size >= (size_t)NWAVE * sizeof(float)) {
        float* part = (float*)d_ws;
        ssim_stream<<<grid, block, 0, stream>>>(pred, targ, part, nullptr);
        ssim_finish<<<1, 256, 0, stream>>>(part, out);
    } else {
        ssim_zero<<<1, 1, 0, stream>>>(out);
        ssim_stream<<<grid, block, 0, stream>>>(pred, targ, nullptr, out);
        ssim_finish_atomic<<<1, 1, 0, stream>>>(out);
    }
}